// Round 2
// baseline (2225.434 us; speedup 1.0000x reference)
//
#include <hip/hip_runtime.h>
#include <hip/hip_bf16.h>

typedef __hip_bfloat16 bf16;
typedef __attribute__((ext_vector_type(8))) short bf16x8;
typedef __attribute__((ext_vector_type(4))) float f32x4;

#define MCH 18432   // pixels per chunk (96 rows * 192 cols)

__device__ __forceinline__ float tof(bf16 x){ return __bfloat162float(x); }
__device__ __forceinline__ bf16  tob(float x){ return __float2bfloat16(x); }

// ---------------- weight transpose+convert kernels (f32 -> bf16, run once per launch) ----------------
__global__ __launch_bounds__(256) void kt_w1(const float* __restrict__ Wvqk, const float* __restrict__ Wvv,
                                             bf16* __restrict__ W1T){
  int idx = blockIdx.x*256 + threadIdx.x;            // 1152*384
  int c = idx/384, k = idx - (idx/384)*384;
  W1T[idx] = tob((c < 768) ? Wvqk[k*768 + c] : Wvv[k*384 + (c-768)]);
}
__global__ __launch_bounds__(256) void kt_w2(const float* __restrict__ Wcqk, bf16* __restrict__ WcT){
  int idx = blockIdx.x*256 + threadIdx.x;            // 768*128
  int c = idx >> 7, k = idx & 127;
  WcT[idx] = tob(Wcqk[k*768 + c]);
}
__global__ __launch_bounds__(256) void kt_w3(const float* __restrict__ Wov, bf16* __restrict__ WoT){
  int idx = blockIdx.x*256 + threadIdx.x;            // 384*384
  int c = idx/384, k = idx - (idx/384)*384;
  WoT[idx] = tob(Wov[k*384 + c]);
}

// ---------------- unified MFMA GEMM ----------------
// MODE 0: A = values f32 (rolled gather, K=384), W1T (N=1152) -> rawQ/K/V bf16 [8][MCH][48]
// MODE 1: A = coords f32 (rolled gather, K=128), WcT (N=768)  -> rawQC/KC bf16 [8][MCH][48]
// MODE 2: A = y_att bf16 (direct rows, K=384),   WoT (N=384)  -> d_out f32
template<int MODE>
__global__ __launch_bounds__(256) void gemm_k(const float* __restrict__ Af, const bf16* __restrict__ Ab,
    const bf16* __restrict__ WT, const float* __restrict__ bias0, const float* __restrict__ bias1,
    bf16* __restrict__ out0, bf16* __restrict__ out1, bf16* __restrict__ out2,
    float* __restrict__ outf, int bb, int hf)
{
  constexpr int KTOT = (MODE==1) ? 128 : 384;
  constexpr int KST  = (MODE==1) ? 128 : 192;
  constexpr int LDA  = KST + 8;     // pad to break power-of-2 LDS stride
  constexpr int ACH  = KST/8;       // 8-elem chunks per row
  __shared__ bf16 As[64][LDA];
  __shared__ bf16 Ws[128][LDA];
  const int tid = threadIdx.x;
  const int coltile = blockIdx.x, rowtile = blockIdx.y;
  const int wid = tid >> 6, lane = tid & 63;
  const int wr = (wid >> 1) * 32, wc = (wid & 1) * 64;   // 2x2 waves -> 64x128 tile

  f32x4 acc[2][4] = {};

  for (int ks = 0; ks < KTOT; ks += KST) {
    __syncthreads();
    // stage A tile [64 x KST] (f32 -> bf16 for MODE 0/1)
    for (int idx = tid; idx < 64*ACH; idx += 256) {
      int r = idx / ACH, cc = idx - (idx/ACH)*ACH;
      int pix = rowtile*64 + r;
      if constexpr (MODE == 2) {
        const bf16* src = Ab + (size_t)pix*384 + ks + cc*8;
        *(uint4*)(&As[r][cc*8]) = *(const uint4*)src;
      } else {
        int lr = pix/192, lc = pix - (pix/192)*192;
        int prow = (96*hf + lr + 4) % 192;   // jnp.roll(t,-4): out[i]=in[(i+4)%n]
        int pcol = (lc + 4) % 192;
        constexpr int FD = (MODE==0) ? 384 : 128;
        const float* src = Af + (((size_t)bb*192 + prow)*192 + pcol)*FD + ks + cc*8;
        float4 f0 = *(const float4*)(src);
        float4 f1 = *(const float4*)(src+4);
        union { bf16 h[8]; uint4 u; } t;
        t.h[0]=tob(f0.x); t.h[1]=tob(f0.y); t.h[2]=tob(f0.z); t.h[3]=tob(f0.w);
        t.h[4]=tob(f1.x); t.h[5]=tob(f1.y); t.h[6]=tob(f1.z); t.h[7]=tob(f1.w);
        *(uint4*)(&As[r][cc*8]) = t.u;
      }
    }
    // stage W^T tile [128 x KST]  (WT is [N][KTOT] bf16, pre-transposed)
    for (int idx = tid; idx < 128*ACH; idx += 256) {
      int n = idx / ACH, cc = idx - (idx/ACH)*ACH;
      int c = coltile*128 + n;
      *(uint4*)(&Ws[n][cc*8]) = *(const uint4*)(WT + (size_t)c*KTOT + ks + cc*8);
    }
    __syncthreads();
    #pragma unroll
    for (int k2 = 0; k2 < KST; k2 += 32) {
      int kk = k2 + (lane >> 4)*8;   // A/B frag: m/n = lane&15, k = (lane>>4)*8+j
      int ml = lane & 15;
      bf16x8 a0 = *(const bf16x8*)(&As[wr + ml][kk]);
      bf16x8 a1 = *(const bf16x8*)(&As[wr + 16 + ml][kk]);
      bf16x8 b0 = *(const bf16x8*)(&Ws[wc + ml][kk]);
      bf16x8 b1 = *(const bf16x8*)(&Ws[wc + 16 + ml][kk]);
      bf16x8 b2 = *(const bf16x8*)(&Ws[wc + 32 + ml][kk]);
      bf16x8 b3 = *(const bf16x8*)(&Ws[wc + 48 + ml][kk]);
      acc[0][0] = __builtin_amdgcn_mfma_f32_16x16x32_bf16(a0, b0, acc[0][0], 0, 0, 0);
      acc[0][1] = __builtin_amdgcn_mfma_f32_16x16x32_bf16(a0, b1, acc[0][1], 0, 0, 0);
      acc[0][2] = __builtin_amdgcn_mfma_f32_16x16x32_bf16(a0, b2, acc[0][2], 0, 0, 0);
      acc[0][3] = __builtin_amdgcn_mfma_f32_16x16x32_bf16(a0, b3, acc[0][3], 0, 0, 0);
      acc[1][0] = __builtin_amdgcn_mfma_f32_16x16x32_bf16(a1, b0, acc[1][0], 0, 0, 0);
      acc[1][1] = __builtin_amdgcn_mfma_f32_16x16x32_bf16(a1, b1, acc[1][1], 0, 0, 0);
      acc[1][2] = __builtin_amdgcn_mfma_f32_16x16x32_bf16(a1, b2, acc[1][2], 0, 0, 0);
      acc[1][3] = __builtin_amdgcn_mfma_f32_16x16x32_bf16(a1, b3, acc[1][3], 0, 0, 0);
    }
  }
  // epilogue: C/D layout col=lane&15, row=(lane>>4)*4+reg  [verified m89/m91]
  const int lrow = (lane >> 4) * 4, lcol = lane & 15;
  #pragma unroll
  for (int sr=0; sr<2; sr++)
  #pragma unroll
  for (int sc2=0; sc2<4; sc2++) {
    f32x4 av = acc[sr][sc2];
    #pragma unroll
    for (int i=0;i<4;i++) {
      int row = wr + sr*16 + lrow + i;
      int col = wc + sc2*16 + lcol;
      int pix = rowtile*64 + row;
      int c = coltile*128 + col;
      float v = av[i];
      if constexpr (MODE == 0) {
        // combined flat index c over [vqk(768) | vv(384)]; q/k/v interleaved: flat[3d+role]
        v += (c < 768) ? bias0[c] : bias1[c - 768];
        int d = c/3, role = c - (c/3)*3;
        int hh = d & 7, e = d >> 3;        // d = e*8 + h (feature layout '(e H)')
        bf16* dst = (role==0) ? out0 : (role==1) ? out1 : out2;
        dst[((size_t)hh*MCH + pix)*48 + e] = tob(v);
      } else if constexpr (MODE == 1) {
        v += bias0[c];
        int d = c >> 1, role = c & 1;      // qc/kc interleaved: flat[2d+role]
        int hh = d & 7, e = d >> 3;
        (role ? out1 : out0)[((size_t)hh*MCH + pix)*48 + e] = tob(v);
      } else {
        v += bias0[c];
        int lr = pix/192, lc = pix - (pix/192)*192;
        // output at window coords (reference never un-rolls), feature layout '(H e)'
        outf[(((size_t)bb*192 + 96*hf + lr)*192 + lc)*384 + c] = v;
      }
    }
  }
}

// ---------------- RMS factors (sumsq over the 768 raw vqk / cqk outputs) ----------------
__global__ __launch_bounds__(256) void norm_k(const bf16* __restrict__ rawQ, const bf16* __restrict__ rawK,
    const bf16* __restrict__ rawV, const bf16* __restrict__ rawQC, const bf16* __restrict__ rawKC,
    float* __restrict__ rms_v, float* __restrict__ rms_c)
{
  const int w = threadIdx.x >> 6, lane = threadIdx.x & 63;
  const int pix = blockIdx.x*4 + w;
  float sv = 0.f;
  #pragma unroll
  for (int i2=0;i2<4;i2++) {           // vqk cols <-> (h, e<32) over q/k/v
    int idx = lane + 64*i2;            // 256 = 8h * 32e
    size_t a = ((size_t)(idx>>5)*MCH + pix)*48 + (idx&31);
    float q = tof(rawQ[a]), k = tof(rawK[a]), v = tof(rawV[a]);
    sv += q*q + k*k + v*v;
  }
  float sc = 0.f;
  #pragma unroll
  for (int i2=0;i2<6;i2++) {           // cqk cols <-> (h, all e) over qc/kc
    int idx = lane + 64*i2;            // 384 = 8h * 48e
    int h2 = idx/48, e2 = idx - (idx/48)*48;
    size_t a = ((size_t)h2*MCH + pix)*48 + e2;
    float q = tof(rawQC[a]), k = tof(rawKC[a]);
    sc += q*q + k*k;
  }
  #pragma unroll
  for (int m=32; m>0; m>>=1){ sv += __shfl_xor(sv, m); sc += __shfl_xor(sc, m); }
  if (lane == 0) {
    rms_v[pix] = rsqrtf(sv*(1.f/768.f) + 1e-6f);
    rms_c[pix] = rsqrtf(sc*(1.f/768.f) + 1e-6f);
  }
}

// ---------------- windowed attention, one block per (window, head) ----------------
__global__ __launch_bounds__(256) void attn_k(const bf16* __restrict__ rawQ, const bf16* __restrict__ rawK,
    const bf16* __restrict__ rawV, const bf16* __restrict__ rawQC, const bf16* __restrict__ rawKC,
    const float* __restrict__ rms_v, const float* __restrict__ rms_c,
    const float* __restrict__ g_vqk, const float* __restrict__ g_cqk,
    const float* __restrict__ lam_p, const float* __restrict__ pos_emb,
    bf16* __restrict__ y_att, int hf)
{
  __shared__ float q_s[64][49], k_s[64][49], v_s[64][49], qc_s[64][49], kc_s[64][49];
  __shared__ float S[64][65];
  __shared__ float rv[64], rc[64];
  const int tid = threadIdx.x;
  const int win = blockIdx.x, hh = blockIdx.y;
  const int wxl = win/24, wy = win - (win/24)*24;

  if (tid < 64) {
    int pix = (wxl*8 + (tid>>3))*192 + wy*8 + (tid&7);
    rv[tid] = rms_v[pix];
    rc[tid] = rms_c[pix];
  }
  __syncthreads();

  for (int idx = tid; idx < 3072; idx += 256) {
    int j = idx/48, e = idx - (idx/48)*48;
    int pix = (wxl*8 + (j>>3))*192 + wy*8 + (j&7);
    size_t a = ((size_t)hh*MCH + pix)*48 + e;
    int d = e*8 + hh;
    float qv = tof(rawQ[a]), kv = tof(rawK[a]), vv = tof(rawV[a]);
    if (e < 32) {                      // d<256: from normalized vqk (rms * g); else raw vv path
      float r = rv[j];
      qv *= r * g_vqk[3*d];
      kv *= r * g_vqk[3*d+1];
      vv *= r * g_vqk[3*d+2];
    }
    q_s[j][e] = qv; k_s[j][e] = kv; v_s[j][e] = vv;
    float rr = rc[j];
    qc_s[j][e] = tof(rawQC[a]) * rr * g_cqk[2*d];
    kc_s[j][e] = tof(rawKC[a]) * rr * g_cqk[2*d+1];
  }
  __syncthreads();

  const float lam = lam_p[0];
  const int i = tid >> 2, jg = tid & 3;
  const bool rowm = (hf*12 + wxl) == 23;   // last window row -> row_mask
  const bool colm = (wy == 23);            // last window col -> col_mask

  float sv[16], sc[16];
  #pragma unroll
  for (int t=0;t<16;t++){ sv[t]=0.f; sc[t]=0.f; }
  for (int eb=0; eb<48; eb+=8) {
    float qb[8], qcb[8];
    #pragma unroll
    for (int t=0;t<8;t++){ qb[t]=q_s[i][eb+t]; qcb[t]=qc_s[i][eb+t]; }
    #pragma unroll
    for (int jj=0;jj<16;jj++) {
      int j = jg*16 + jj;
      float a1 = sv[jj], a2 = sc[jj];
      #pragma unroll
      for (int t=0;t<8;t++){ a1 += qb[t]*k_s[j][eb+t]; a2 += qcb[t]*kc_s[j][eb+t]; }
      sv[jj]=a1; sc[jj]=a2;
    }
  }
  const float scale = 0.14433756729740643f;   // 1/sqrt(48)
  const int txi = i>>3, tyi = i&7;
  #pragma unroll
  for (int jj=0;jj<16;jj++) {
    int j = jg*16 + jj;
    int txj = j>>3, tyj = j&7;
    float s = (sv[jj] + lam*sc[jj]) * scale + pos_emb[(txj-txi+7)*15 + (tyj-tyi+7)];
    if ((rowm && ((txi>=4) != (txj>=4))) || (colm && ((tyi>=4) != (tyj>=4)))) s = -1e30f;
    S[i][j] = s;
  }
  __syncthreads();

  if (tid < 64) {
    float mx = -1e30f;
    for (int j=0;j<64;j++) mx = fmaxf(mx, S[tid][j]);
    float sum = 0.f;
    for (int j=0;j<64;j++){ float e2 = __expf(S[tid][j]-mx); S[tid][j]=e2; sum+=e2; }
    float inv = 1.f/sum;
    for (int j=0;j<64;j++) S[tid][j] *= inv;
  }
  __syncthreads();

  const int eg = tid & 3;
  float oacc[12];
  #pragma unroll
  for (int t=0;t<12;t++) oacc[t]=0.f;
  for (int j=0;j<64;j++) {
    float s = S[i][j];
    #pragma unroll
    for (int t=0;t<12;t++) oacc[t] += s * v_s[j][eg*12+t];
  }
  int pix = (wxl*8 + (i>>3))*192 + wy*8 + (i&7);
  #pragma unroll
  for (int t=0;t<12;t++)
    y_att[(size_t)pix*384 + hh*48 + eg*12 + t] = tob(oacc[t]);   // output feature layout '(H e)'
}

extern "C" void kernel_launch(void* const* d_in, const int* in_sizes, int n_in,
                              void* d_out, int out_size, void* d_ws, size_t ws_size,
                              hipStream_t stream)
{
  const float* values = (const float*)d_in[0];
  const float* coords = (const float*)d_in[1];
  const float* W_vqk  = (const float*)d_in[2];
  const float* b_vqk  = (const float*)d_in[3];
  const float* g_vqk  = (const float*)d_in[4];
  const float* W_vv   = (const float*)d_in[5];
  const float* b_vv   = (const float*)d_in[6];
  const float* W_cqk  = (const float*)d_in[7];
  const float* b_cqk  = (const float*)d_in[8];
  const float* g_cqk  = (const float*)d_in[9];
  const float* lam    = (const float*)d_in[10];
  const float* pos    = (const float*)d_in[11];
  const float* W_ov   = (const float*)d_in[12];
  const float* b_ov   = (const float*)d_in[13];
  float* out = (float*)d_out;

  char* ws = (char*)d_ws;
  bf16* W1T   = (bf16*)(ws + 0);          // 1152*384*2 = 884736
  bf16* WcT   = (bf16*)(ws + 884736);     // 768*128*2  = 196608
  bf16* WoT   = (bf16*)(ws + 1081344);    // 384*384*2  = 294912
  bf16* rawQ  = (bf16*)(ws + 1376256);    // 8*MCH*48*2 = 14155776 each
  bf16* rawK  = (bf16*)(ws + 15532032);
  bf16* rawV  = (bf16*)(ws + 29687808);
  bf16* rawQC = (bf16*)(ws + 43843584);
  bf16* rawKC = (bf16*)(ws + 57999360);
  float* rms_v = (float*)(ws + 72155136); // MCH*4
  float* rms_c = (float*)(ws + 72228864);
  bf16* y_att = (bf16*)(ws + 72302592);   // MCH*384*2   -> total 86458368 bytes
  (void)ws_size; (void)in_sizes; (void)n_in; (void)out_size;

  kt_w1<<<1728, 256, 0, stream>>>(W_vqk, W_vv, W1T);
  kt_w2<<<384,  256, 0, stream>>>(W_cqk, WcT);
  kt_w3<<<576,  256, 0, stream>>>(W_ov, WoT);

  for (int bb = 0; bb < 2; bb++)
  for (int hf = 0; hf < 2; hf++) {
    gemm_k<0><<<dim3(9,288), 256, 0, stream>>>(values, nullptr, W1T, b_vqk, b_vv, rawQ, rawK, rawV, nullptr, bb, hf);
    gemm_k<1><<<dim3(6,288), 256, 0, stream>>>(coords, nullptr, WcT, b_cqk, nullptr, rawQC, rawKC, nullptr, nullptr, bb, hf);
    norm_k<<<4608, 256, 0, stream>>>(rawQ, rawK, rawV, rawQC, rawKC, rms_v, rms_c);
    attn_k<<<dim3(288,8), 256, 0, stream>>>(rawQ, rawK, rawV, rawQC, rawKC, rms_v, rms_c,
                                            g_vqk, g_cqk, lam, pos, y_att, hf);
    gemm_k<2><<<dim3(3,288), 256, 0, stream>>>(nullptr, y_att, WoT, b_ov, nullptr, nullptr, nullptr, nullptr, out, bb, hf);
  }
}

// Round 3
// 1334.611 us; speedup vs baseline: 1.6675x; 1.6675x over previous
//
#include <hip/hip_runtime.h>
#include <hip/hip_bf16.h>

typedef __hip_bfloat16 bf16;
typedef __attribute__((ext_vector_type(8))) short bf16x8;
typedef __attribute__((ext_vector_type(4))) short bf16x4;
typedef __attribute__((ext_vector_type(4))) float f32x4;

#define CPIX 12288          // pixels per chunk (64 rows * 192 cols)

__device__ __forceinline__ float tof(bf16 x){ return __bfloat162float(x); }
__device__ __forceinline__ bf16  tob(float x){ return __float2bfloat16(x); }
__device__ __forceinline__ float bf2f(short s){ return __uint_as_float(((unsigned)(unsigned short)s) << 16); }

// ---------------- weight permute+convert (f32 -> bf16), one kernel, once per launch ----------------
// Packed channel order: n = role*384 + h*48 + e.  Source col:
//   values path: e<32 -> W_vqk col 24e+3h+role (normalized part); e>=32 -> W_vv col 24e+3h+role-768
//   coords path: role in {0,1} -> W_cqk col 16e+2h+role
__global__ __launch_bounds__(256) void wprep_k(
    const float* __restrict__ W_vqk, const float* __restrict__ W_vv, const float* __restrict__ W_cqk,
    const float* __restrict__ W_ov,  const float* __restrict__ b_vqk, const float* __restrict__ b_vv,
    const float* __restrict__ b_cqk, const float* __restrict__ g_vqk, const float* __restrict__ g_cqk,
    bf16* __restrict__ W1Tp, bf16* __restrict__ WcTp, bf16* __restrict__ WoT,
    float* __restrict__ bP0, float* __restrict__ bPc, float* __restrict__ gvP, float* __restrict__ gcP)
{
  int idx = blockIdx.x*256 + threadIdx.x;
  if (idx < 442368) {                     // W1Tp [1152][384]
    int n = idx/384, k = idx - n*384;
    int role = n/384, rem = n - role*384, h = rem/48, e = rem - (rem/48)*48;
    int c = 24*e + 3*h + role;
    float v = (e < 32) ? W_vqk[k*768 + c] : W_vv[k*384 + (c - 768)];
    W1Tp[n*384 + k] = tob(v);
  } else if (idx < 540672) {              // WcTp [768][128]
    int q = idx - 442368;
    int n = q >> 7, k = q & 127;
    int role = n/384, rem = n - role*384, h = rem/48, e = rem - (rem/48)*48;
    WcTp[n*128 + k] = tob(W_cqk[k*768 + 16*e + 2*h + role]);
  } else if (idx < 688128) {              // WoT [384][384]
    int q = idx - 540672;
    int n = q/384, k = q - n*384;
    WoT[n*384 + k] = tob(W_ov[k*384 + n]);
  } else if (idx < 689280) {              // bP0 [1152]
    int n = idx - 688128;
    int role = n/384, rem = n - role*384, h = rem/48, e = rem - (rem/48)*48;
    int c = 24*e + 3*h + role;
    bP0[n] = (e < 32) ? b_vqk[c] : b_vv[c - 768];
  } else if (idx < 690048) {              // bPc [768]
    int n = idx - 689280;
    int role = n/384, rem = n - role*384, h = rem/48, e = rem - (rem/48)*48;
    bPc[n] = b_cqk[16*e + 2*h + role];
  } else if (idx < 691200) {              // gvP [1152]: 1.0 for raw (e>=32) channels
    int n = idx - 690048;
    int role = n/384, rem = n - role*384, h = rem/48, e = rem - (rem/48)*48;
    gvP[n] = (e < 32) ? g_vqk[24*e + 3*h + role] : 1.0f;
  } else if (idx < 691968) {              // gcP [768]
    int n = idx - 691200;
    int role = n/384, rem = n - role*384, h = rem/48, e = rem - (rem/48)*48;
    gcP[n] = g_cqk[16*e + 2*h + role];
  }
}

// ---------------- per-chunk prep: rolled gather + f32->bf16 ----------------
__global__ __launch_bounds__(256) void prep_k(const float* __restrict__ vals, const float* __restrict__ crds,
                                              bf16* __restrict__ Vb, bf16* __restrict__ Cb, int bb, int hf)
{
  int u = blockIdx.x*256 + threadIdx.x;   // 786432 units of 8 elems
  int pix, c8;
  const float* src; bf16* dst;
  if (u < 589824) { pix = u/48; c8 = u - pix*48; }
  else { int u2 = u - 589824; pix = u2 >> 4; c8 = u2 & 15; }
  int lr = pix/192, lc = pix - (pix/192)*192;
  int srow = (hf*64 + lr + 4) % 192;      // jnp.roll(t,-4): out[i]=in[(i+4)%n]
  int scol = (lc + 4) % 192;
  if (u < 589824) { src = vals + (((size_t)bb*192 + srow)*192 + scol)*384 + c8*8; dst = Vb + (size_t)pix*384 + c8*8; }
  else            { src = crds + (((size_t)bb*192 + srow)*192 + scol)*128 + c8*8; dst = Cb + (size_t)pix*128 + c8*8; }
  float4 f0 = *(const float4*)src;
  float4 f1 = *(const float4*)(src + 4);
  union { bf16 h[8]; uint4 u4; } t;
  t.h[0]=tob(f0.x); t.h[1]=tob(f0.y); t.h[2]=tob(f0.z); t.h[3]=tob(f0.w);
  t.h[4]=tob(f1.x); t.h[5]=tob(f1.y); t.h[6]=tob(f1.z); t.h[7]=tob(f1.w);
  *(uint4*)dst = t.u4;
}

// ---------------- MFMA GEMM, 128x128 tile, BK=64 ----------------
// MODE 0: Vb[CPIX][384] @ W1Tp -> Y0 [CPIX][1152] bf16 (+bias), grid (3,96), 3 coltiles/block
// MODE 1: Cb[CPIX][128] @ WcTp -> Yc [CPIX][768]  bf16 (+bias), grid (2,96), 3 coltiles/block
// MODE 2: y_att[CPIX][384] @ WoT -> out f32 (+bias), grid (3,96), 1 coltile/block
template<int MODE>
__global__ __launch_bounds__(256,3) void gemm_k(const bf16* __restrict__ A, const bf16* __restrict__ WT,
    const float* __restrict__ biasP, bf16* __restrict__ outb, float* __restrict__ outf, int pix0)
{
  constexpr int KTOT = (MODE==1) ? 128 : 384;
  constexpr int CTPB = (MODE==2) ? 1 : 3;
  constexpr int NT   = (MODE==0) ? 1152 : (MODE==1) ? 768 : 384;
  __shared__ bf16 As[128][72];      // +8 pad: 2-way-max bank aliasing on b128 reads
  __shared__ bf16 Bs[128][72];
  const int tid = threadIdx.x, lane = tid & 63, wid = tid >> 6;
  const int wr = (wid >> 1)*64, wc = (wid & 1)*64;     // 2x2 waves, 64x64 each
  const int rowbase = blockIdx.y*128;

  for (int ct = 0; ct < CTPB; ct++) {
    const int nbase = (blockIdx.x*CTPB + ct)*128;
    f32x4 acc[4][4] = {};
    for (int ks = 0; ks < KTOT; ks += 64) {
      __syncthreads();
      #pragma unroll
      for (int it = 0; it < 4; it++) {
        int idx = it*256 + tid;           // 1024 chunks of 8 bf16
        int r = idx >> 3, c = idx & 7;
        *(uint4*)&As[r][c*8] = *(const uint4*)(A  + (size_t)(rowbase + r)*KTOT + ks + c*8);
        *(uint4*)&Bs[r][c*8] = *(const uint4*)(WT + (size_t)(nbase  + r)*KTOT + ks + c*8);
      }
      __syncthreads();
      #pragma unroll
      for (int k2 = 0; k2 < 64; k2 += 32) {
        const int kb = k2 + (lane >> 4)*8, ml = lane & 15;
        bf16x8 a[4], b[4];
        #pragma unroll
        for (int t = 0; t < 4; t++) {
          a[t] = *(const bf16x8*)&As[wr + t*16 + ml][kb];
          b[t] = *(const bf16x8*)&Bs[wc + t*16 + ml][kb];
        }
        #pragma unroll
        for (int mt = 0; mt < 4; mt++)
        #pragma unroll
        for (int nt = 0; nt < 4; nt++)
          acc[mt][nt] = __builtin_amdgcn_mfma_f32_16x16x32_bf16(a[mt], b[nt], acc[mt][nt], 0, 0, 0);
      }
    }
    // epilogue: C/D layout col=lane&15, row=(lane>>4)*4+reg
    const int lr4 = (lane >> 4)*4, lcol = lane & 15;
    #pragma unroll
    for (int mt = 0; mt < 4; mt++)
    #pragma unroll
    for (int nt = 0; nt < 4; nt++) {
      f32x4 av = acc[mt][nt];
      int n = nbase + wc + nt*16 + lcol;
      float bv = biasP[n];
      #pragma unroll
      for (int i = 0; i < 4; i++) {
        int pix = rowbase + wr + mt*16 + lr4 + i;
        float v = av[i] + bv;
        if constexpr (MODE == 2) outf[(size_t)(pix0 + pix)*384 + n] = v;
        else                     outb[(size_t)pix*NT + n] = tob(v);
      }
    }
  }
}

// ---------------- RMS factors: coalesced row reads of Y0/Yc ----------------
__global__ __launch_bounds__(256) void norm_k(const bf16* __restrict__ Y0, const bf16* __restrict__ Yc,
                                              float* __restrict__ rms_v, float* __restrict__ rms_c)
{
  const int w = threadIdx.x >> 6, lane = threadIdx.x & 63;
  const int pix = blockIdx.x*4 + w;
  const unsigned* r0 = (const unsigned*)(Y0 + (size_t)pix*1152);
  float sv = 0.f;
  #pragma unroll
  for (int it = 0; it < 9; it++) {
    int p = it*64 + lane;
    unsigned u = r0[p];
    int e0 = (2*p) % 48;                  // e0 even -> both elems share e<32 mask
    if (e0 < 32) {
      float x0 = bf2f((short)(u & 0xffff)), x1 = bf2f((short)(u >> 16));
      sv += x0*x0 + x1*x1;
    }
  }
  const unsigned* r1 = (const unsigned*)(Yc + (size_t)pix*768);
  float sc = 0.f;
  #pragma unroll
  for (int it = 0; it < 6; it++) {
    unsigned u = r1[it*64 + lane];
    float x0 = bf2f((short)(u & 0xffff)), x1 = bf2f((short)(u >> 16));
    sc += x0*x0 + x1*x1;
  }
  #pragma unroll
  for (int m = 32; m > 0; m >>= 1) { sv += __shfl_xor(sv, m); sc += __shfl_xor(sc, m); }
  if (lane == 0) {
    rms_v[pix] = rsqrtf(sv*(1.f/768.f) + 1e-6f);
    rms_c[pix] = rsqrtf(sc*(1.f/768.f) + 1e-6f);
  }
}

// ---------------- windowed attention: block per (window, head) ----------------
__global__ __launch_bounds__(256) void attn_k(const bf16* __restrict__ Y0, const bf16* __restrict__ Yc,
    const float* __restrict__ rms_v, const float* __restrict__ rms_c,
    const float* __restrict__ gvP, const float* __restrict__ gcP,
    const float* __restrict__ lam_p, const float* __restrict__ pos,
    bf16* __restrict__ y_att, int hf)
{
  __shared__ float q_s[64][100];    // q' = [qv*rms*g*SCL | qc*rms_c*gc*lam*SCL]
  __shared__ bf16  k_s[64][104];    // k' = [kv*rms*g | kc*rms_c*gc]
  __shared__ bf16  v_s[64][56];
  __shared__ float S[64][66];
  __shared__ float rv[64], rc[64];
  const int tid = threadIdx.x;
  const int win = blockIdx.x, h = blockIdx.y;
  const int wx = win/24, wy = win - (win/24)*24;

  if (tid < 64) {
    int p = (wx*8 + (tid>>3))*192 + wy*8 + (tid&7);
    rv[tid] = rms_v[p]; rc[tid] = rms_c[p];
  }
  __syncthreads();
  const float lam = lam_p[0];
  const float SCL = 0.14433756729740643f;   // 1/sqrt(48)

  for (int idx = tid; idx < 3072; idx += 256) {     // values path
    int j = idx/48, e = idx - (idx/48)*48;
    int p = (wx*8 + (j>>3))*192 + wy*8 + (j&7);
    size_t base = (size_t)p*1152 + h*48 + e;
    float qv = tof(Y0[base]), kv = tof(Y0[base+384]), vv = tof(Y0[base+768]);
    float r = (e < 32) ? rv[j] : 1.0f;
    int n = h*48 + e;
    q_s[j][e] = qv * r * gvP[n] * SCL;
    k_s[j][e] = tob(kv * r * gvP[384+n]);
    v_s[j][e] = tob(vv * r * gvP[768+n]);
  }
  for (int idx = tid; idx < 3072; idx += 256) {     // coords path
    int j = idx/48, e = idx - (idx/48)*48;
    int p = (wx*8 + (j>>3))*192 + wy*8 + (j&7);
    size_t base = (size_t)p*768 + h*48 + e;
    float rr = rc[j];
    int n = h*48 + e;
    q_s[j][48+e] = tof(Yc[base]) * rr * gcP[n] * lam * SCL;
    k_s[j][48+e] = tob(tof(Yc[base+384]) * rr * gcP[384+n]);
  }
  __syncthreads();

  // scores: 16x16 thread groups, each 4i x 4j, K=96
  const int i0 = (tid >> 4)*4, j0 = (tid & 15)*4;
  float s[4][4] = {};
  for (int kb = 0; kb < 96; kb += 8) {
    float q[4][8], kf[4][8];
    #pragma unroll
    for (int r = 0; r < 4; r++) {
      float4 qa = *(const float4*)&q_s[i0+r][kb];
      float4 qb = *(const float4*)&q_s[i0+r][kb+4];
      q[r][0]=qa.x; q[r][1]=qa.y; q[r][2]=qa.z; q[r][3]=qa.w;
      q[r][4]=qb.x; q[r][5]=qb.y; q[r][6]=qb.z; q[r][7]=qb.w;
      bf16x8 kv8 = *(const bf16x8*)&k_s[j0+r][kb];
      #pragma unroll
      for (int t = 0; t < 8; t++) kf[r][t] = bf2f(kv8[t]);
    }
    #pragma unroll
    for (int r = 0; r < 4; r++)
    #pragma unroll
    for (int c = 0; c < 4; c++) {
      float a = s[r][c];
      #pragma unroll
      for (int t = 0; t < 8; t++) a += q[r][t]*kf[c][t];
      s[r][c] = a;
    }
  }
  const bool rowm = (hf == 2) && (wx == 7);
  const bool colm = (wy == 23);
  #pragma unroll
  for (int r = 0; r < 4; r++)
  #pragma unroll
  for (int c = 0; c < 4; c++) {
    int i = i0 + r, j = j0 + c;
    int txi = i>>3, tyi = i&7, txj = j>>3, tyj = j&7;
    float val = s[r][c] + pos[(txj-txi+7)*15 + (tyj-tyi+7)];
    if ((rowm && ((txi>=4) != (txj>=4))) || (colm && ((tyi>=4) != (tyj>=4)))) val = -1e30f;
    S[i][j] = val;
  }
  __syncthreads();

  if (tid < 64) {                   // softmax rows (wave 0)
    float mx = -1e30f;
    for (int j = 0; j < 64; j++) mx = fmaxf(mx, S[tid][j]);
    float sum = 0.f;
    for (int j = 0; j < 64; j++) { float e2 = __expf(S[tid][j]-mx); S[tid][j] = e2; sum += e2; }
    float inv = 1.f/sum;
    for (int j = 0; j < 64; j++) S[tid][j] *= inv;
  }
  __syncthreads();

  if (tid < 192) {                  // PV: 16 i-groups x 12 e-groups, each 4i x 4e
    const int ip = (tid/12)*4, e0 = (tid - (tid/12)*12)*4;
    float o[4][4] = {};
    for (int j = 0; j < 64; j++) {
      bf16x4 v4 = *(const bf16x4*)&v_s[j][e0];
      float vf[4];
      #pragma unroll
      for (int c = 0; c < 4; c++) vf[c] = bf2f(v4[c]);
      #pragma unroll
      for (int r = 0; r < 4; r++) {
        float sv4 = S[ip+r][j];
        #pragma unroll
        for (int c = 0; c < 4; c++) o[r][c] += sv4 * vf[c];
      }
    }
    #pragma unroll
    for (int r = 0; r < 4; r++) {
      int i = ip + r;
      int p = (wx*8 + (i>>3))*192 + wy*8 + (i&7);
      union { bf16 hx[4]; uint2 u2; } t;
      #pragma unroll
      for (int c = 0; c < 4; c++) t.hx[c] = tob(o[r][c]);
      *(uint2*)(y_att + (size_t)p*384 + h*48 + e0) = t.u2;
    }
  }
}

extern "C" void kernel_launch(void* const* d_in, const int* in_sizes, int n_in,
                              void* d_out, int out_size, void* d_ws, size_t ws_size,
                              hipStream_t stream)
{
  const float* values = (const float*)d_in[0];
  const float* coords = (const float*)d_in[1];
  const float* W_vqk  = (const float*)d_in[2];
  const float* b_vqk  = (const float*)d_in[3];
  const float* g_vqk  = (const float*)d_in[4];
  const float* W_vv   = (const float*)d_in[5];
  const float* b_vv   = (const float*)d_in[6];
  const float* W_cqk  = (const float*)d_in[7];
  const float* b_cqk  = (const float*)d_in[8];
  const float* g_cqk  = (const float*)d_in[9];
  const float* lam    = (const float*)d_in[10];
  const float* pos    = (const float*)d_in[11];
  const float* W_ov   = (const float*)d_in[12];
  const float* b_ov   = (const float*)d_in[13];
  float* out = (float*)d_out;

  char* ws = (char*)d_ws;
  bf16*  W1Tp  = (bf16*)(ws + 0);           // 1152*384*2   = 884736
  bf16*  WcTp  = (bf16*)(ws + 884736);      // 768*128*2    = 196608
  bf16*  WoT   = (bf16*)(ws + 1081344);     // 384*384*2    = 294912
  float* bP0   = (float*)(ws + 1376256);    // 1152*4
  float* bPc   = (float*)(ws + 1380864);    // 768*4
  float* gvP   = (float*)(ws + 1383936);    // 1152*4
  float* gcP   = (float*)(ws + 1388544);    // 768*4
  bf16*  Vb    = (bf16*)(ws + 1391616);     // CPIX*384*2   = 9437184
  bf16*  Cb    = (bf16*)(ws + 10828800);    // CPIX*128*2   = 3145728
  bf16*  Y0    = (bf16*)(ws + 13974528);    // CPIX*1152*2  = 28311552
  bf16*  Yc    = (bf16*)(ws + 42286080);    // CPIX*768*2   = 18874368
  float* rms_v = (float*)(ws + 61160448);   // CPIX*4
  float* rms_c = (float*)(ws + 61209600);   // CPIX*4
  bf16*  y_att = (bf16*)(ws + 61258752);    // CPIX*384*2   = 9437184 -> total 70695936
  (void)ws_size; (void)in_sizes; (void)n_in; (void)out_size;

  wprep_k<<<2703, 256, 0, stream>>>(W_vqk, W_vv, W_cqk, W_ov, b_vqk, b_vv, b_cqk, g_vqk, g_cqk,
                                    W1Tp, WcTp, WoT, bP0, bPc, gvP, gcP);

  for (int ch = 0; ch < 6; ch++) {
    int bb = ch/3, hf = ch - bb*3;
    prep_k<<<3072, 256, 0, stream>>>(values, coords, Vb, Cb, bb, hf);
    gemm_k<0><<<dim3(3,96), 256, 0, stream>>>(Vb, W1Tp, bP0, Y0, nullptr, 0);
    gemm_k<1><<<dim3(2,96), 256, 0, stream>>>(Cb, WcTp, bPc, Yc, nullptr, 0);
    norm_k<<<3072, 256, 0, stream>>>(Y0, Yc, rms_v, rms_c);
    attn_k<<<dim3(192,8), 256, 0, stream>>>(Y0, Yc, rms_v, rms_c, gvP, gcP, lam, pos, y_att, hf);
    gemm_k<2><<<dim3(3,96), 256, 0, stream>>>(y_att, WoT, b_ov, nullptr, out, ch*CPIX);
  }
}